// Round 16
// baseline (83.388 us; speedup 1.0000x reference)
//
#include <hip/hip_runtime.h>

#define D 64
#define BSH 6            // bucket shift: 64 nodes per bucket
#define BSZ 64           // nodes per bucket
#define NBMAX 2048       // max buckets (nodes <= 131072)
#define TILE 8192        // edges per block in bucket passes (proven)
#define CAP  1536        // LDS edge-staging capacity (mean ~1024, 16 sigma)
#define PADM (BSZ * 3)   // max pad per bucket (192)
#define SRTC (CAP + PADM + 8)

typedef unsigned int   uint;
typedef unsigned short ushort_t;
typedef __attribute__((ext_vector_type(8))) short bf16x8;
typedef __attribute__((ext_vector_type(4))) float f32x4;

__device__ __forceinline__ ushort_t f2bf(float f) {
    uint u = __float_as_uint(f);
    u += 0x7FFFu + ((u >> 16) & 1u);           // round-to-nearest-even
    return (ushort_t)(u >> 16);
}

// ---------------------------------------------------------------------------
// A1. Bucket histogram (bucket = dst>>6) on the first nbA blocks; bf16
//     conversion of x spread across ALL blocks. Block 0 zeroes xb row
//     n_nodes (the gather pad target).
// ---------------------------------------------------------------------------
__global__ __launch_bounds__(256) void k_bhist(
    const int* __restrict__ dst, int* __restrict__ bucketCount,
    int* __restrict__ blockBase, const float4* __restrict__ x4,
    uint4* __restrict__ xb4, int n8, int nb, int nbA, int n_edges)
{
    __shared__ int hist[NBMAX];
    const int tid = threadIdx.x;
    const int blk = blockIdx.x;
    const bool doHist = (blk < nbA);

    if (doHist) {
        for (int i = tid; i < nb; i += 256) hist[i] = 0;
    }
    __syncthreads();

    if (blk == 0 && tid < 8) {
        uint4 z; z.x = z.y = z.z = z.w = 0u;
        xb4[n8 + tid] = z;
    }

    {
        const int chunk = (n8 + gridDim.x - 1) / gridDim.x;
        const int lo = blk * chunk;
        const int hi = min(n8, lo + chunk);
        for (int t = lo + tid; t < hi; t += 256) {
            float4 a = x4[t * 2];
            float4 c = x4[t * 2 + 1];
            uint4 o;
            o.x = (uint)f2bf(a.x) | ((uint)f2bf(a.y) << 16);
            o.y = (uint)f2bf(a.z) | ((uint)f2bf(a.w) << 16);
            o.z = (uint)f2bf(c.x) | ((uint)f2bf(c.y) << 16);
            o.w = (uint)f2bf(c.z) | ((uint)f2bf(c.w) << 16);
            xb4[t] = o;
        }
    }

    if (!doHist) return;

    const int e0 = blk * TILE;
    const int n4 = n_edges >> 2;
    const int4* dst4 = (const int4*)dst;
#pragma unroll
    for (int k = 0; k < TILE / 1024; ++k) {
        int i4 = (e0 >> 2) + k * 256 + tid;
        if (i4 < n4) {
            int4 d = dst4[i4];
            atomicAdd(&hist[d.x >> BSH], 1);
            atomicAdd(&hist[d.y >> BSH], 1);
            atomicAdd(&hist[d.z >> BSH], 1);
            atomicAdd(&hist[d.w >> BSH], 1);
        }
    }
    if (blk == nbA - 1) {
        for (int e = (n4 << 2) + tid; e < n_edges; e += 256)
            atomicAdd(&hist[dst[e] >> BSH], 1);
    }
    __syncthreads();
    for (int i = tid; i < nb; i += 256)
        blockBase[(size_t)blk * nb + i] = atomicAdd(&bucketCount[i], hist[i]);
}

// ---------------------------------------------------------------------------
// A2. Scatter packed (src | dstLocal<<24) into bucket-grouped runs.
//     Redundant per-block LDS scan of bucketCount; block 0 publishes
//     bucketBase.
// ---------------------------------------------------------------------------
__global__ __launch_bounds__(256) void k_bscatter(
    const int* __restrict__ src, const int* __restrict__ dst,
    const int* __restrict__ bucketCount, const int* __restrict__ blockBase,
    int* __restrict__ bucketBase, int* __restrict__ packed,
    int nb, int n_edges)
{
    __shared__ int sc[NBMAX];
    __shared__ int cur[NBMAX];
    __shared__ int ts[256];
    const int tid = threadIdx.x;
    const int blk = blockIdx.x;

    {
        const int base = tid * 8;
        int v[8];
#pragma unroll
        for (int k = 0; k < 8; ++k)
            v[k] = (base + k < nb) ? bucketCount[base + k] : 0;
        int tsum = 0;
#pragma unroll
        for (int k = 0; k < 8; ++k) tsum += v[k];
        ts[tid] = tsum;
        __syncthreads();
        for (int off = 1; off < 256; off <<= 1) {
            int t = (tid >= off) ? ts[tid - off] : 0;
            __syncthreads();
            ts[tid] += t;
            __syncthreads();
        }
        int run = ts[tid] - tsum;
#pragma unroll
        for (int k = 0; k < 8; ++k) {
            if (base + k < nb) sc[base + k] = run;
            run += v[k];
        }
    }
    __syncthreads();

    if (blk == 0) {
        for (int i = tid; i <= nb; i += 256)
            bucketBase[i] = (i < nb) ? sc[i] : n_edges;
    }

    for (int i = tid; i < nb; i += 256)
        cur[i] = sc[i] + blockBase[(size_t)blk * nb + i];
    __syncthreads();

    const int e0 = blk * TILE;
    const int n4 = n_edges >> 2;
    const int4* src4 = (const int4*)src;
    const int4* dst4 = (const int4*)dst;
#pragma unroll
    for (int k = 0; k < TILE / 1024; ++k) {
        int i4 = (e0 >> 2) + k * 256 + tid;
        if (i4 < n4) {
            int4 sv = src4[i4];
            int4 dv = dst4[i4];
            int p;
            p = atomicAdd(&cur[dv.x >> BSH], 1); packed[p] = sv.x | ((dv.x & (BSZ-1)) << 24);
            p = atomicAdd(&cur[dv.y >> BSH], 1); packed[p] = sv.y | ((dv.y & (BSZ-1)) << 24);
            p = atomicAdd(&cur[dv.z >> BSH], 1); packed[p] = sv.z | ((dv.z & (BSZ-1)) << 24);
            p = atomicAdd(&cur[dv.w >> BSH], 1); packed[p] = sv.w | ((dv.w & (BSZ-1)) << 24);
        }
    }
    if (blk == gridDim.x - 1) {
        for (int e = (n4 << 2) + tid; e < n_edges; e += 256) {
            int p = atomicAdd(&cur[dst[e] >> BSH], 1);
            packed[p] = src[e] | ((dst[e] & (BSZ-1)) << 24);
        }
    }
}

// ---------------------------------------------------------------------------
// B1. Per-bucket CSR sort (LDS) -> padded esrcP in global (coalesced write),
//     per-node padded offsets pofs + true degrees pdeg. One block per
//     64-node bucket, 256 thr, ~16KB LDS -> 8 blocks/CU (high occupancy).
//     Bucket b's padded region starts at bucketBase[b] + PADM*b.
// ---------------------------------------------------------------------------
__global__ __launch_bounds__(256) void k_sort(
    const int* __restrict__ packed, const int* __restrict__ bucketBase,
    int* __restrict__ esrcP, int* __restrict__ pofs, int* __restrict__ pdeg,
    int n_nodes)
{
    __shared__ int raw[CAP];
    __shared__ int srt[SRTC];
    __shared__ int ldeg[BSZ];
    __shared__ int lofs[BSZ];
    __shared__ int cur[BSZ];

    const int tid = threadIdx.x;
    const int bucket = blockIdx.x;
    const int ebase = bucketBase[bucket];
    const int ecnt  = bucketBase[bucket + 1] - ebase;
    const int gbase = ebase + PADM * bucket;
    const bool fits = (ecnt <= CAP);
    const int zrow = n_nodes;

    if (tid < BSZ) ldeg[tid] = 0;
    __syncthreads();

    // Stage + degree histogram.
    if (fits) {
        for (int i = tid; i < ecnt; i += 256) {
            int pk = packed[ebase + i];
            raw[i] = pk;
            atomicAdd(&ldeg[((uint)pk) >> 24], 1);
        }
    } else {
        for (int i = tid; i < ecnt; i += 256)
            atomicAdd(&ldeg[((uint)packed[ebase + i]) >> 24], 1);
    }
    __syncthreads();

    // Exclusive scan of counts padded to x4 (first 64 threads).
    {
        int v = 0;
        if (tid < BSZ) { v = (ldeg[tid] + 3) & ~3; lofs[tid] = v; }
        __syncthreads();
        for (int off = 1; off < BSZ; off <<= 1) {
            int t = (tid < BSZ && tid >= off) ? lofs[tid - off] : 0;
            __syncthreads();
            if (tid < BSZ) lofs[tid] += t;
            __syncthreads();
        }
        if (tid < BSZ) { int e = lofs[tid] - v; lofs[tid] = e; cur[tid] = e; }
    }
    __syncthreads();

    if (fits) {
        // Sort into padded LDS segments, fill pads, copy out coalesced.
        for (int i = tid; i < ecnt; i += 256) {
            int pk = raw[i];
            int pos = atomicAdd(&cur[((uint)pk) >> 24], 1);
            srt[pos] = pk & 0x00FFFFFF;
        }
        if (tid < BSZ) {
            int base = lofs[tid] + ldeg[tid];
            int end  = lofs[tid] + ((ldeg[tid] + 3) & ~3);
            for (int i = base; i < end; ++i) srt[i] = zrow;
        }
        __syncthreads();
        const int ptot = lofs[BSZ - 1] + ((ldeg[BSZ - 1] + 3) & ~3);
        for (int i = tid; i < ptot; i += 256) esrcP[gbase + i] = srt[i];
    } else {
        // Fallback (never hit): sort straight to global.
        for (int i = tid; i < ecnt; i += 256) {
            int pk = packed[ebase + i];
            int pos = atomicAdd(&cur[((uint)pk) >> 24], 1);
            esrcP[gbase + pos] = pk & 0x00FFFFFF;
        }
        __syncthreads();
        if (tid < BSZ) {
            int base = lofs[tid] + ldeg[tid];
            int end  = lofs[tid] + ((ldeg[tid] + 3) & ~3);
            for (int i = base; i < end; ++i) esrcP[gbase + i] = zrow;
        }
    }

    if (tid < BSZ) {
        int node = (bucket << BSH) + tid;     // < nb*64, array sized for it
        pofs[node] = gbase + lofs[tid];
        pdeg[node] = ldeg[tid];
    }
}

// ---------------------------------------------------------------------------
// B2. Wave-autonomous gather + MFMA. One block = 4 waves = 4 independent
//     16-node tiles; 16KB LDS (Wl 8K + 4x2K private h tiles) -> 8 blocks/CU
//     = 32 waves. After the single Wl barrier there is NO synchronization:
//     each wave gathers its 16 nodes (8-lane groups, uint4, pad-free inner
//     loop), writes h to its private LDS tile (same-wave ordering), and runs
//     the proven MFMA epilogue.
// ---------------------------------------------------------------------------
__global__ __launch_bounds__(256, 8) void k_gather(
    const int* __restrict__ esrcP, const int* __restrict__ pofs,
    const int* __restrict__ pdeg, const uint4* __restrict__ xb4,
    const float* __restrict__ W, const float* __restrict__ bvec,
    float* __restrict__ out, int n_nodes)
{
    __shared__ ushort_t Wl[64 * 64];                 // bf16 W, swizzled
    __shared__ __align__(16) char hst[4][2048];      // per-wave h tiles

    const int tid = threadIdx.x;

    // Stage W (fp32 -> bf16) with byte ^= (row&7)<<4 swizzle.
    for (int item = tid; item < 512; item += 256) {
        const int o = item >> 3;
        const int j = (item & 7) * 8;
        const float* wp = W + o * 64 + j;
        float4 wa = *(const float4*)wp;
        float4 wb = *(const float4*)(wp + 4);
        uint4 w4;
        w4.x = (uint)f2bf(wa.x) | ((uint)f2bf(wa.y) << 16);
        w4.y = (uint)f2bf(wa.z) | ((uint)f2bf(wa.w) << 16);
        w4.z = (uint)f2bf(wb.x) | ((uint)f2bf(wb.y) << 16);
        w4.w = (uint)f2bf(wb.z) | ((uint)f2bf(wb.w) << 16);
        *(uint4*)((char*)Wl + o * 128 + ((j * 2) ^ ((o & 7) << 4))) = w4;
    }
    __syncthreads();

    const int wave = tid >> 6;
    const int lane = tid & 63;
    const int g    = lane >> 3;        // node group 0..7
    const int f8   = lane & 7;         // uint4 index within row

#define CVLO(u) __uint_as_float((u) << 16)
#define CVHI(u) __uint_as_float((u) & 0xFFFF0000u)

    const uint4* __restrict__ xbf = xb4 + f8;
    char* hwb = hst[wave];
    const int tile = blockIdx.x * 4 + wave;
    const int node0 = tile * 16;

#pragma unroll
    for (int p = 0; p < 2; ++p) {
        const int nl = p * 8 + g;                // row in wave tile 0..15
        const int node = node0 + nl;             // < nb*64 by construction
        const int cnt = pdeg[node];
        const int eb  = pofs[node];
        const int pc  = (cnt + 3) & ~3;

        float s0 = 0.f, s1 = 0.f, s2 = 0.f, s3 = 0.f;
        float s4 = 0.f, s5 = 0.f, s6 = 0.f, s7 = 0.f;

        for (int i = 0; i < pc; i += 4) {
            uint vv[4];
#pragma unroll
            for (int k = 0; k < 4; ++k) vv[k] = (uint)esrcP[eb + i + k];
            uint4 A[4];
#pragma unroll
            for (int k = 0; k < 4; ++k)
                A[k] = xbf[(size_t)vv[k] * 8];
#pragma unroll
            for (int k = 0; k < 4; ++k) {
                s0 += CVLO(A[k].x);
                s1 += CVHI(A[k].x);
                s2 += CVLO(A[k].y);
                s3 += CVHI(A[k].y);
                s4 += CVLO(A[k].z);
                s5 += CVHI(A[k].z);
                s6 += CVLO(A[k].w);
                s7 += CVHI(A[k].w);
            }
        }

        uint4 hreg; hreg.x = hreg.y = hreg.z = hreg.w = 0u;
        if (node < n_nodes) {
            uint4 xv = xbf[(size_t)node * 8];     // bf16 self term
            float rinv = 1.0f / (float)(cnt + 1);
            float h0 = (s0 + CVLO(xv.x)) * rinv;
            float h1 = (s1 + CVHI(xv.x)) * rinv;
            float h2 = (s2 + CVLO(xv.y)) * rinv;
            float h3 = (s3 + CVHI(xv.y)) * rinv;
            float h4 = (s4 + CVLO(xv.z)) * rinv;
            float h5 = (s5 + CVHI(xv.z)) * rinv;
            float h6 = (s6 + CVLO(xv.w)) * rinv;
            float h7 = (s7 + CVHI(xv.w)) * rinv;
            hreg.x = (uint)f2bf(h0) | ((uint)f2bf(h1) << 16);
            hreg.y = (uint)f2bf(h2) | ((uint)f2bf(h3) << 16);
            hreg.z = (uint)f2bf(h4) | ((uint)f2bf(h5) << 16);
            hreg.w = (uint)f2bf(h6) | ((uint)f2bf(h7) << 16);
        }
        *(uint4*)(hwb + nl * 128 + ((f8 * 16) ^ ((nl & 7) << 4))) = hreg;
    }
#undef CVLO
#undef CVHI

    // MFMA epilogue (same wave wrote the tile -> program order suffices).
    const int m  = lane & 15;
    const int kg = lane >> 4;
    bf16x8 a0 = *(const bf16x8*)(hwb + m * 128 + (((kg * 16)     ) ^ ((m & 7) << 4)));
    bf16x8 a1 = *(const bf16x8*)(hwb + m * 128 + (((64 + kg * 16)) ^ ((m & 7) << 4)));

#pragma unroll
    for (int c = 0; c < 4; ++c) {
        const int o = c * 16 + m;
        bf16x8 b0 = *(const bf16x8*)((char*)Wl + o * 128 + (((kg * 16)     ) ^ ((o & 7) << 4)));
        bf16x8 b1 = *(const bf16x8*)((char*)Wl + o * 128 + (((64 + kg * 16)) ^ ((o & 7) << 4)));
        f32x4 acc = {0.f, 0.f, 0.f, 0.f};
        acc = __builtin_amdgcn_mfma_f32_16x16x32_bf16(a0, b0, acc, 0, 0, 0);
        acc = __builtin_amdgcn_mfma_f32_16x16x32_bf16(a1, b1, acc, 0, 0, 0);
        const float bias = bvec[o];
#pragma unroll
        for (int r = 0; r < 4; ++r) {
            int row = node0 + kg * 4 + r;
            if (row < n_nodes)
                out[(size_t)row * 64 + o] = acc[r] + bias;
        }
    }
}

extern "C" void kernel_launch(void* const* d_in, const int* in_sizes, int n_in,
                              void* d_out, int out_size, void* d_ws, size_t ws_size,
                              hipStream_t stream)
{
    const float* x   = (const float*)d_in[0];
    const int*   src = (const int*)d_in[1];
    const int*   dst = (const int*)d_in[2];
    const float* W   = (const float*)d_in[3];
    const float* b   = (const float*)d_in[4];
    float* out = (float*)d_out;

    const int n_nodes = in_sizes[0] / D;
    const int n_edges = in_sizes[1];
    const int nb  = (n_nodes + BSZ - 1) >> BSH;      // 64-node buckets (1563)
    const int nbA = (n_edges + TILE - 1) / TILE;     // histogram blocks (196)

    // Workspace: [xb (N+1)*64 bf16][bucketCount NBMAX][bucketBase NBMAX+1]
    //            [blockBase nbA*nb][packed E][esrcP E+PADM*nb]
    //            [pofs nb*64][pdeg nb*64]
    ushort_t* xb = (ushort_t*)d_ws;
    int* bucketCount = (int*)(xb + (size_t)(n_nodes + 1) * D);
    int* bucketBase  = bucketCount + NBMAX;
    int* blockBase   = bucketBase + NBMAX + 1;
    int* packed      = blockBase + (size_t)nbA * nb;
    int* esrcP       = packed + n_edges;
    int* pofs        = esrcP + n_edges + (size_t)PADM * nb;
    int* pdeg        = pofs + (size_t)nb * BSZ;

    hipMemsetAsync(bucketCount, 0, NBMAX * sizeof(int), stream);

    const int n8 = n_nodes * D / 8;
    const int nbConv = (n8 + 1023) / 1024;
    const int gridA = max(nbA, nbConv);
    k_bhist   <<<gridA, 256, 0, stream>>>(dst, bucketCount, blockBase,
                                          (const float4*)x, (uint4*)xb, n8, nb, nbA, n_edges);
    k_bscatter<<<nbA, 256, 0, stream>>>(src, dst, bucketCount, blockBase,
                                        bucketBase, packed, nb, n_edges);
    k_sort    <<<nb,  256, 0, stream>>>(packed, bucketBase, esrcP, pofs, pdeg, n_nodes);
    k_gather  <<<nb,  256, 0, stream>>>(esrcP, pofs, pdeg, (const uint4*)xb,
                                        W, b, out, n_nodes);
}

// Round 17
// 77.478 us; speedup vs baseline: 1.0763x; 1.0763x over previous
//
#include <hip/hip_runtime.h>

#define D 64
#define BSH 6            // bucket shift: 64 nodes per bucket
#define BSZ 64           // nodes per bucket
#define NBMAX 2048       // max buckets (nodes <= 131072)
#define STILE 4096       // edges per block in the scatter pass (391 blocks)
#define CAPB 2048        // fixed bucket region stride (mean 1024, +32 sigma)
#define CAP  1536        // LDS edge-staging capacity in aggcsr (16 sigma)
#define SRTC 2056        // sorted+padded capacity (>= 8KB for h-staging reuse)

typedef unsigned int   uint;
typedef unsigned short ushort_t;
typedef __attribute__((ext_vector_type(8))) short bf16x8;
typedef __attribute__((ext_vector_type(4))) float f32x4;

__device__ __forceinline__ ushort_t f2bf(float f) {
    uint u = __float_as_uint(f);
    u += 0x7FFFu + ((u >> 16) & 1u);           // round-to-nearest-even
    return (ushort_t)(u >> 16);
}

// ---------------------------------------------------------------------------
// 0. x (fp32) -> xb (bf16 packed); block 0 zeroes the pad row and gcnt.
// ---------------------------------------------------------------------------
__global__ __launch_bounds__(256) void k_conv(
    const float4* __restrict__ x4, uint4* __restrict__ xb4,
    int* __restrict__ gcnt, int n8, int nb)
{
    const int tid = threadIdx.x;
    int t = blockIdx.x * 256 + tid;
    if (t < n8) {
        float4 a = x4[t * 2];
        float4 c = x4[t * 2 + 1];
        uint4 o;
        o.x = (uint)f2bf(a.x) | ((uint)f2bf(a.y) << 16);
        o.y = (uint)f2bf(a.z) | ((uint)f2bf(a.w) << 16);
        o.z = (uint)f2bf(c.x) | ((uint)f2bf(c.y) << 16);
        o.w = (uint)f2bf(c.z) | ((uint)f2bf(c.w) << 16);
        xb4[t] = o;
    }
    if (blockIdx.x == 0) {
        if (tid < 8) {                         // zero pad row (xb row n_nodes)
            uint4 z; z.x = z.y = z.z = z.w = 0u;
            xb4[n8 + tid] = z;
        }
        for (int i = tid; i < nb; i += 256) gcnt[i] = 0;
    }
}

// ---------------------------------------------------------------------------
// 1. One-pass scatter into FIXED-STRIDE bucket regions (no histogram
//    pre-pass, no scan, no blockBase). Per block: LDS-hist its tile ->
//    one global atomicAdd per touched bucket to reserve a run -> scatter
//    packed (src | dstLocal<<24) at bucket*CAPB + pos. Cross-block order
//    within a bucket is irrelevant (aggcsr re-sorts in LDS).
//    CAPB = 2048 is +32 sigma over the 1024-mean bucket load; pass-2 clamps
//    defensively (drops edges only on pathological inputs).
// ---------------------------------------------------------------------------
__global__ __launch_bounds__(256) void k_scatter1p(
    const int* __restrict__ src, const int* __restrict__ dst,
    int* __restrict__ gcnt, int* __restrict__ packedB,
    int nb, int n_edges)
{
    __shared__ int hist[NBMAX];
    const int tid = threadIdx.x;
    const int blk = blockIdx.x;
    for (int i = tid; i < nb; i += 256) hist[i] = 0;
    __syncthreads();

    const int e0 = blk * STILE;
    const int n4 = n_edges >> 2;
    const int4* src4 = (const int4*)src;
    const int4* dst4 = (const int4*)dst;

    // Pass 1: tile-local bucket histogram.
#pragma unroll
    for (int k = 0; k < STILE / 1024; ++k) {
        int i4 = (e0 >> 2) + k * 256 + tid;
        if (i4 < n4) {
            int4 d = dst4[i4];
            atomicAdd(&hist[d.x >> BSH], 1);
            atomicAdd(&hist[d.y >> BSH], 1);
            atomicAdd(&hist[d.z >> BSH], 1);
            atomicAdd(&hist[d.w >> BSH], 1);
        }
    }
    if (blk == gridDim.x - 1) {
        for (int e = (n4 << 2) + tid; e < n_edges; e += 256)
            atomicAdd(&hist[dst[e] >> BSH], 1);
    }
    __syncthreads();

    // Reserve: hist[i] becomes this block's global cursor for bucket i.
    for (int i = tid; i < nb; i += 256) {
        int c = hist[i];
        if (c) hist[i] = atomicAdd(&gcnt[i], c);
    }
    __syncthreads();

    // Pass 2: scatter (tile data is L2-hot from pass 1).
#pragma unroll
    for (int k = 0; k < STILE / 1024; ++k) {
        int i4 = (e0 >> 2) + k * 256 + tid;
        if (i4 < n4) {
            int4 sv = src4[i4];
            int4 dv = dst4[i4];
            int b, p;
            b = dv.x >> BSH; p = atomicAdd(&hist[b], 1);
            if (p < CAPB) packedB[(size_t)b * CAPB + p] = sv.x | ((dv.x & (BSZ-1)) << 24);
            b = dv.y >> BSH; p = atomicAdd(&hist[b], 1);
            if (p < CAPB) packedB[(size_t)b * CAPB + p] = sv.y | ((dv.y & (BSZ-1)) << 24);
            b = dv.z >> BSH; p = atomicAdd(&hist[b], 1);
            if (p < CAPB) packedB[(size_t)b * CAPB + p] = sv.z | ((dv.z & (BSZ-1)) << 24);
            b = dv.w >> BSH; p = atomicAdd(&hist[b], 1);
            if (p < CAPB) packedB[(size_t)b * CAPB + p] = sv.w | ((dv.w & (BSZ-1)) << 24);
        }
    }
    if (blk == gridDim.x - 1) {
        for (int e = (n4 << 2) + tid; e < n_edges; e += 256) {
            int b = dst[e] >> BSH;
            int p = atomicAdd(&hist[b], 1);
            if (p < CAPB) packedB[(size_t)b * CAPB + p] = src[e] | ((dst[e] & (BSZ-1)) << 24);
        }
    }
}

// ---------------------------------------------------------------------------
// B. Fused per-bucket CSR + aggregate + MFMA GEMM + bias (r14-proven).
//    One block per 64-node bucket (512 thr, 8 waves, ~23KB LDS). Gather:
//    8 edge-groups x 8 lanes, uint4 loads; serial per-node walk, pad to x4
//    with the zero row; no masks, no clamps, no cross-lane reduce.
// ---------------------------------------------------------------------------
__global__ __launch_bounds__(512, 8) void k_aggcsr(
    const int* __restrict__ packedB, const int* __restrict__ gcnt,
    const uint4* __restrict__ xb4, const float* __restrict__ W,
    const float* __restrict__ bvec, float* __restrict__ out, int n_nodes)
{
    __shared__ int raw[CAP];
    __shared__ int srt[SRTC];             // sorted+padded; reused for h-staging
    __shared__ ushort_t Wl[64 * 64];      // bf16 W, XOR-swizzled rows
    __shared__ int ldeg[BSZ];
    __shared__ int lofs[BSZ];
    __shared__ int cur[BSZ];

    const int tid = threadIdx.x;
    const int bucket = blockIdx.x;
    const int ebase = bucket * CAPB;
    const int ecnt  = min(gcnt[bucket], CAPB);
    const bool fits = (ecnt <= CAP);
    const uint nmax = (uint)(n_nodes - 1);
    const int zrow = n_nodes;             // zeroed xb row for padding

    // Phase 0: stage W (fp32 -> bf16) into LDS with byte ^= (row&7)<<4 swizzle.
    {
        const int o = tid >> 3;            // row 0..63
        const int j = (tid & 7) * 8;       // col 0..56
        const float* wp = W + o * 64 + j;
        float4 wa = *(const float4*)wp;
        float4 wb = *(const float4*)(wp + 4);
        uint4 w4;
        w4.x = (uint)f2bf(wa.x) | ((uint)f2bf(wa.y) << 16);
        w4.y = (uint)f2bf(wa.z) | ((uint)f2bf(wa.w) << 16);
        w4.z = (uint)f2bf(wb.x) | ((uint)f2bf(wb.y) << 16);
        w4.w = (uint)f2bf(wb.z) | ((uint)f2bf(wb.w) << 16);
        *(uint4*)((char*)Wl + o * 128 + ((j * 2) ^ ((o & 7) << 4))) = w4;
    }
    if (tid < BSZ) ldeg[tid] = 0;
    __syncthreads();

    // Phase 1: stage edges + degree histogram.
    if (fits) {
        for (int i = tid; i < ecnt; i += 512) {
            int pk = packedB[ebase + i];
            raw[i] = pk;
            atomicAdd(&ldeg[((uint)pk) >> 24], 1);
        }
    } else {
        for (int i = tid; i < ecnt; i += 512)
            atomicAdd(&ldeg[((uint)packedB[ebase + i]) >> 24], 1);
    }
    __syncthreads();

    // Phase 2: exclusive scan of counts padded to x4 (first 64 threads).
    {
        int v = 0;
        if (tid < BSZ) { v = (ldeg[tid] + 3) & ~3; lofs[tid] = v; }
        __syncthreads();
        for (int off = 1; off < BSZ; off <<= 1) {
            int t = (tid < BSZ && tid >= off) ? lofs[tid - off] : 0;
            __syncthreads();
            if (tid < BSZ) lofs[tid] += t;
            __syncthreads();
        }
        if (tid < BSZ) { int e = lofs[tid] - v; lofs[tid] = e; cur[tid] = e; }
    }
    __syncthreads();

    // Phase 3: sort esrc into padded LDS segments + fill pads with zrow.
    if (fits) {
        for (int i = tid; i < ecnt; i += 512) {
            int pk = raw[i];
            int pos = atomicAdd(&cur[((uint)pk) >> 24], 1);
            srt[pos] = pk & 0x00FFFFFF;
        }
        if (tid < BSZ) {
            int base = lofs[tid] + ldeg[tid];
            int end  = lofs[tid] + ((ldeg[tid] + 3) & ~3);
            for (int i = base; i < end; ++i) srt[i] = zrow;
        }
    }
    __syncthreads();

    // Phase 4: gather. Wave w owns nodes w*8..w*8+7; group g (8 lanes) walks
    // node w*8+g serially; each lane holds 8 feats (uint4).
    const int wave = tid >> 6;
    const int lane = tid & 63;
    const int g    = lane >> 3;        // node group 0..7
    const int f8   = lane & 7;         // uint4 index within row (8 feats)

#define CVLO(u) __uint_as_float((u) << 16)
#define CVHI(u) __uint_as_float((u) & 0xFFFF0000u)

    const uint4* __restrict__ xbf = xb4 + f8;

    const int nl = wave * 8 + g;
    const int node = (bucket << BSH) + nl;
    const bool valid = (node < n_nodes);
    const int cnt = valid ? ldeg[nl] : 0;
    const int eb  = valid ? lofs[nl] : 0;
    const int pc  = (cnt + 3) & ~3;

    float s0 = 0.f, s1 = 0.f, s2 = 0.f, s3 = 0.f;
    float s4 = 0.f, s5 = 0.f, s6 = 0.f, s7 = 0.f;

    if (fits) {
        for (int i = 0; i < pc; i += 4) {
            uint vv[4];
#pragma unroll
            for (int k = 0; k < 4; ++k) vv[k] = (uint)srt[eb + i + k];
            uint4 A[4];
#pragma unroll
            for (int k = 0; k < 4; ++k)
                A[k] = xbf[(size_t)vv[k] * 8];
#pragma unroll
            for (int k = 0; k < 4; ++k) {
                s0 += CVLO(A[k].x);
                s1 += CVHI(A[k].x);
                s2 += CVLO(A[k].y);
                s3 += CVHI(A[k].y);
                s4 += CVLO(A[k].z);
                s5 += CVHI(A[k].z);
                s6 += CVLO(A[k].w);
                s7 += CVHI(A[k].w);
            }
        }
    } else {
        // Fallback (never hit for this input): masked scan of bucket.
        const int nlm = valid ? nl : -1;
        for (int i = 0; i < ecnt; ++i) {
            int pk = packedB[ebase + i];
            float m0 = ((int)(((uint)pk) >> 24) == nlm) ? 1.0f : 0.0f;
            uint4 A0 = xbf[(size_t)min((uint)(pk & 0x00FFFFFF), nmax) * 8];
            s0 = fmaf(m0, CVLO(A0.x), s0);
            s1 = fmaf(m0, CVHI(A0.x), s1);
            s2 = fmaf(m0, CVLO(A0.y), s2);
            s3 = fmaf(m0, CVHI(A0.y), s3);
            s4 = fmaf(m0, CVLO(A0.z), s4);
            s5 = fmaf(m0, CVHI(A0.z), s5);
            s6 = fmaf(m0, CVLO(A0.w), s6);
            s7 = fmaf(m0, CVHI(A0.w), s7);
        }
    }

    uint4 hreg; hreg.x = hreg.y = hreg.z = hreg.w = 0u;
    if (valid) {
        uint4 xv = xbf[(size_t)node * 8];            // bf16 self term
        float rinv = 1.0f / (float)(cnt + 1);
        float h0 = (s0 + CVLO(xv.x)) * rinv;
        float h1 = (s1 + CVHI(xv.x)) * rinv;
        float h2 = (s2 + CVLO(xv.y)) * rinv;
        float h3 = (s3 + CVHI(xv.y)) * rinv;
        float h4 = (s4 + CVLO(xv.z)) * rinv;
        float h5 = (s5 + CVHI(xv.z)) * rinv;
        float h6 = (s6 + CVLO(xv.w)) * rinv;
        float h7 = (s7 + CVHI(xv.w)) * rinv;
        hreg.x = (uint)f2bf(h0) | ((uint)f2bf(h1) << 16);
        hreg.y = (uint)f2bf(h2) | ((uint)f2bf(h3) << 16);
        hreg.z = (uint)f2bf(h4) | ((uint)f2bf(h5) << 16);
        hreg.w = (uint)f2bf(h6) | ((uint)f2bf(h7) << 16);
    }
#undef CVLO
#undef CVHI

    // All waves done with srt -> reuse it as the shared 64x64 bf16 h tile.
    __syncthreads();

    char* hstage = (char*)srt;               // 64 rows x 128B, swizzled
    *(uint4*)(hstage + nl * 128 + ((f8 * 16) ^ ((nl & 7) << 4))) = hreg;
    __syncthreads();

    // MFMA epilogue: waves 0..3 each handle one 16-node tile.
    if (wave < 4) {
        char* hwb = hstage + wave * 2048;
        const int m  = lane & 15;
        const int kg = lane >> 4;
        bf16x8 a0 = *(const bf16x8*)(hwb + m * 128 + (((kg * 16)     ) ^ ((m & 7) << 4)));
        bf16x8 a1 = *(const bf16x8*)(hwb + m * 128 + (((64 + kg * 16)) ^ ((m & 7) << 4)));

        const int node0 = (bucket << BSH) + wave * 16;
#pragma unroll
        for (int c = 0; c < 4; ++c) {
            const int o = c * 16 + m;
            bf16x8 b0 = *(const bf16x8*)((char*)Wl + o * 128 + (((kg * 16)     ) ^ ((o & 7) << 4)));
            bf16x8 b1 = *(const bf16x8*)((char*)Wl + o * 128 + (((64 + kg * 16)) ^ ((o & 7) << 4)));
            f32x4 acc = {0.f, 0.f, 0.f, 0.f};
            acc = __builtin_amdgcn_mfma_f32_16x16x32_bf16(a0, b0, acc, 0, 0, 0);
            acc = __builtin_amdgcn_mfma_f32_16x16x32_bf16(a1, b1, acc, 0, 0, 0);
            const float bias = bvec[o];
#pragma unroll
            for (int r = 0; r < 4; ++r) {
                int row = node0 + kg * 4 + r;
                if (row < n_nodes)
                    out[(size_t)row * 64 + o] = acc[r] + bias;
            }
        }
    }
}

extern "C" void kernel_launch(void* const* d_in, const int* in_sizes, int n_in,
                              void* d_out, int out_size, void* d_ws, size_t ws_size,
                              hipStream_t stream)
{
    const float* x   = (const float*)d_in[0];
    const int*   src = (const int*)d_in[1];
    const int*   dst = (const int*)d_in[2];
    const float* W   = (const float*)d_in[3];
    const float* b   = (const float*)d_in[4];
    float* out = (float*)d_out;

    const int n_nodes = in_sizes[0] / D;
    const int n_edges = in_sizes[1];
    const int nb  = (n_nodes + BSZ - 1) >> BSH;      // 64-node buckets (1563)
    const int nbS = (n_edges + STILE - 1) / STILE;   // scatter blocks (391)

    // Workspace: [xb (N+1)*64 bf16][gcnt NBMAX][packedB nb*CAPB]
    ushort_t* xb = (ushort_t*)d_ws;
    int* gcnt    = (int*)(xb + (size_t)(n_nodes + 1) * D);
    int* packedB = gcnt + NBMAX;

    const int n8 = n_nodes * D / 8;
    k_conv     <<<(n8 + 255) / 256, 256, 0, stream>>>((const float4*)x, (uint4*)xb,
                                                      gcnt, n8, nb);
    k_scatter1p<<<nbS, 256, 0, stream>>>(src, dst, gcnt, packedB, nb, n_edges);
    k_aggcsr   <<<nb,  512, 0, stream>>>(packedB, gcnt, (const uint4*)xb,
                                         W, b, out, n_nodes);
}

// Round 18
// 74.544 us; speedup vs baseline: 1.1186x; 1.0394x over previous
//
#include <hip/hip_runtime.h>

#define D 64
#define BSH 6            // bucket shift: 64 nodes per bucket
#define BSZ 64           // nodes per bucket
#define NBMAX 2048       // max buckets (nodes <= 131072)
#define STILE 16384      // edges per scatter block (98 blocks, runs ~10.5 edges)
#define CAPB 2048        // fixed bucket region stride (mean 1024, +32 sigma)
#define CAP  1536        // LDS edge-staging capacity in aggcsr (16 sigma)
#define SRTC 2056        // sorted+padded capacity (>= 8KB for h-staging reuse)

typedef unsigned int   uint;
typedef unsigned short ushort_t;
typedef __attribute__((ext_vector_type(8))) short bf16x8;
typedef __attribute__((ext_vector_type(4))) float f32x4;

__device__ __forceinline__ ushort_t f2bf(float f) {
    uint u = __float_as_uint(f);
    u += 0x7FFFu + ((u >> 16) & 1u);           // round-to-nearest-even
    return (ushort_t)(u >> 16);
}

// ---------------------------------------------------------------------------
// 1. Fused conv + one-pass scatter. ALL blocks (391) convert an x slice
//    (full-BW conv); blocks < nbS additionally scatter their 16K-edge tile
//    into fixed-stride bucket regions (LDS hist -> one global atomicAdd per
//    touched bucket -> scatter). Long runs (~10.5 edges) cut partial-line
//    write amplification ~6x -> ~2.4x vs STILE 4096.
// ---------------------------------------------------------------------------
__global__ __launch_bounds__(512) void k_scatconv(
    const float4* __restrict__ x4, uint4* __restrict__ xb4,
    const int* __restrict__ src, const int* __restrict__ dst,
    int* __restrict__ gcnt, int* __restrict__ packedB,
    int n8, int nb, int nbS, int n_edges)
{
    __shared__ int hist[NBMAX];
    const int tid = threadIdx.x;
    const int blk = blockIdx.x;

    // Zero pad row (xb row n_nodes) once.
    if (blk == 0 && tid < 8) {
        uint4 z; z.x = z.y = z.z = z.w = 0u;
        xb4[n8 + tid] = z;
    }

    // bf16 conversion slice over ALL blocks (coalesced, full BW).
    {
        const int chunk = (n8 + gridDim.x - 1) / gridDim.x;
        const int lo = blk * chunk;
        const int hi = min(n8, lo + chunk);
        for (int t = lo + tid; t < hi; t += 512) {
            float4 a = x4[t * 2];
            float4 c = x4[t * 2 + 1];
            uint4 o;
            o.x = (uint)f2bf(a.x) | ((uint)f2bf(a.y) << 16);
            o.y = (uint)f2bf(a.z) | ((uint)f2bf(a.w) << 16);
            o.z = (uint)f2bf(c.x) | ((uint)f2bf(c.y) << 16);
            o.w = (uint)f2bf(c.z) | ((uint)f2bf(c.w) << 16);
            xb4[t] = o;
        }
    }

    if (blk >= nbS) return;

    for (int i = tid; i < nb; i += 512) hist[i] = 0;
    __syncthreads();

    const int e0 = blk * STILE;
    const int n4 = n_edges >> 2;
    const int4* src4 = (const int4*)src;
    const int4* dst4 = (const int4*)dst;

    // Pass 1: tile-local bucket histogram.
#pragma unroll
    for (int k = 0; k < STILE / 2048; ++k) {
        int i4 = (e0 >> 2) + k * 512 + tid;
        if (i4 < n4) {
            int4 d = dst4[i4];
            atomicAdd(&hist[d.x >> BSH], 1);
            atomicAdd(&hist[d.y >> BSH], 1);
            atomicAdd(&hist[d.z >> BSH], 1);
            atomicAdd(&hist[d.w >> BSH], 1);
        }
    }
    if (blk == nbS - 1) {
        for (int e = (n4 << 2) + tid; e < n_edges; e += 512)
            atomicAdd(&hist[dst[e] >> BSH], 1);
    }
    __syncthreads();

    // Reserve: hist[i] becomes this block's global cursor for bucket i.
    for (int i = tid; i < nb; i += 512) {
        int c = hist[i];
        if (c) hist[i] = atomicAdd(&gcnt[i], c);
    }
    __syncthreads();

    // Pass 2: scatter (tile is L2-hot from pass 1).
#pragma unroll
    for (int k = 0; k < STILE / 2048; ++k) {
        int i4 = (e0 >> 2) + k * 512 + tid;
        if (i4 < n4) {
            int4 sv = src4[i4];
            int4 dv = dst4[i4];
            int b, p;
            b = dv.x >> BSH; p = atomicAdd(&hist[b], 1);
            if (p < CAPB) packedB[(size_t)b * CAPB + p] = sv.x | ((dv.x & (BSZ-1)) << 24);
            b = dv.y >> BSH; p = atomicAdd(&hist[b], 1);
            if (p < CAPB) packedB[(size_t)b * CAPB + p] = sv.y | ((dv.y & (BSZ-1)) << 24);
            b = dv.z >> BSH; p = atomicAdd(&hist[b], 1);
            if (p < CAPB) packedB[(size_t)b * CAPB + p] = sv.z | ((dv.z & (BSZ-1)) << 24);
            b = dv.w >> BSH; p = atomicAdd(&hist[b], 1);
            if (p < CAPB) packedB[(size_t)b * CAPB + p] = sv.w | ((dv.w & (BSZ-1)) << 24);
        }
    }
    if (blk == nbS - 1) {
        for (int e = (n4 << 2) + tid; e < n_edges; e += 512) {
            int b = dst[e] >> BSH;
            int p = atomicAdd(&hist[b], 1);
            if (p < CAPB) packedB[(size_t)b * CAPB + p] = src[e] | ((dst[e] & (BSZ-1)) << 24);
        }
    }
}

// ---------------------------------------------------------------------------
// B. Fused per-bucket CSR + aggregate + MFMA GEMM + bias (r14/r17-proven,
//    unchanged). One block per 64-node bucket (512 thr, 8 waves, ~23KB LDS).
// ---------------------------------------------------------------------------
__global__ __launch_bounds__(512, 8) void k_aggcsr(
    const int* __restrict__ packedB, const int* __restrict__ gcnt,
    const uint4* __restrict__ xb4, const float* __restrict__ W,
    const float* __restrict__ bvec, float* __restrict__ out, int n_nodes)
{
    __shared__ int raw[CAP];
    __shared__ int srt[SRTC];             // sorted+padded; reused for h-staging
    __shared__ ushort_t Wl[64 * 64];      // bf16 W, XOR-swizzled rows
    __shared__ int ldeg[BSZ];
    __shared__ int lofs[BSZ];
    __shared__ int cur[BSZ];

    const int tid = threadIdx.x;
    const int bucket = blockIdx.x;
    const int ebase = bucket * CAPB;
    const int ecnt  = min(gcnt[bucket], CAPB);
    const bool fits = (ecnt <= CAP);
    const uint nmax = (uint)(n_nodes - 1);
    const int zrow = n_nodes;             // zeroed xb row for padding

    // Phase 0: stage W (fp32 -> bf16) into LDS with byte ^= (row&7)<<4 swizzle.
    {
        const int o = tid >> 3;            // row 0..63
        const int j = (tid & 7) * 8;       // col 0..56
        const float* wp = W + o * 64 + j;
        float4 wa = *(const float4*)wp;
        float4 wb = *(const float4*)(wp + 4);
        uint4 w4;
        w4.x = (uint)f2bf(wa.x) | ((uint)f2bf(wa.y) << 16);
        w4.y = (uint)f2bf(wa.z) | ((uint)f2bf(wa.w) << 16);
        w4.z = (uint)f2bf(wb.x) | ((uint)f2bf(wb.y) << 16);
        w4.w = (uint)f2bf(wb.z) | ((uint)f2bf(wb.w) << 16);
        *(uint4*)((char*)Wl + o * 128 + ((j * 2) ^ ((o & 7) << 4))) = w4;
    }
    if (tid < BSZ) ldeg[tid] = 0;
    __syncthreads();

    // Phase 1: stage edges + degree histogram.
    if (fits) {
        for (int i = tid; i < ecnt; i += 512) {
            int pk = packedB[ebase + i];
            raw[i] = pk;
            atomicAdd(&ldeg[((uint)pk) >> 24], 1);
        }
    } else {
        for (int i = tid; i < ecnt; i += 512)
            atomicAdd(&ldeg[((uint)packedB[ebase + i]) >> 24], 1);
    }
    __syncthreads();

    // Phase 2: exclusive scan of counts padded to x4 (first 64 threads).
    {
        int v = 0;
        if (tid < BSZ) { v = (ldeg[tid] + 3) & ~3; lofs[tid] = v; }
        __syncthreads();
        for (int off = 1; off < BSZ; off <<= 1) {
            int t = (tid < BSZ && tid >= off) ? lofs[tid - off] : 0;
            __syncthreads();
            if (tid < BSZ) lofs[tid] += t;
            __syncthreads();
        }
        if (tid < BSZ) { int e = lofs[tid] - v; lofs[tid] = e; cur[tid] = e; }
    }
    __syncthreads();

    // Phase 3: sort esrc into padded LDS segments + fill pads with zrow.
    if (fits) {
        for (int i = tid; i < ecnt; i += 512) {
            int pk = raw[i];
            int pos = atomicAdd(&cur[((uint)pk) >> 24], 1);
            srt[pos] = pk & 0x00FFFFFF;
        }
        if (tid < BSZ) {
            int base = lofs[tid] + ldeg[tid];
            int end  = lofs[tid] + ((ldeg[tid] + 3) & ~3);
            for (int i = base; i < end; ++i) srt[i] = zrow;
        }
    }
    __syncthreads();

    // Phase 4: gather. Wave w owns nodes w*8..w*8+7; group g (8 lanes) walks
    // node w*8+g serially; each lane holds 8 feats (uint4).
    const int wave = tid >> 6;
    const int lane = tid & 63;
    const int g    = lane >> 3;        // node group 0..7
    const int f8   = lane & 7;         // uint4 index within row (8 feats)

#define CVLO(u) __uint_as_float((u) << 16)
#define CVHI(u) __uint_as_float((u) & 0xFFFF0000u)

    const uint4* __restrict__ xbf = xb4 + f8;

    const int nl = wave * 8 + g;
    const int node = (bucket << BSH) + nl;
    const bool valid = (node < n_nodes);
    const int cnt = valid ? ldeg[nl] : 0;
    const int eb  = valid ? lofs[nl] : 0;
    const int pc  = (cnt + 3) & ~3;

    float s0 = 0.f, s1 = 0.f, s2 = 0.f, s3 = 0.f;
    float s4 = 0.f, s5 = 0.f, s6 = 0.f, s7 = 0.f;

    if (fits) {
        for (int i = 0; i < pc; i += 4) {
            uint vv[4];
#pragma unroll
            for (int k = 0; k < 4; ++k) vv[k] = (uint)srt[eb + i + k];
            uint4 A[4];
#pragma unroll
            for (int k = 0; k < 4; ++k)
                A[k] = xbf[(size_t)vv[k] * 8];
#pragma unroll
            for (int k = 0; k < 4; ++k) {
                s0 += CVLO(A[k].x);
                s1 += CVHI(A[k].x);
                s2 += CVLO(A[k].y);
                s3 += CVHI(A[k].y);
                s4 += CVLO(A[k].z);
                s5 += CVHI(A[k].z);
                s6 += CVLO(A[k].w);
                s7 += CVHI(A[k].w);
            }
        }
    } else {
        // Fallback (never hit for this input): masked scan of bucket.
        const int nlm = valid ? nl : -1;
        for (int i = 0; i < ecnt; ++i) {
            int pk = packedB[ebase + i];
            float m0 = ((int)(((uint)pk) >> 24) == nlm) ? 1.0f : 0.0f;
            uint4 A0 = xbf[(size_t)min((uint)(pk & 0x00FFFFFF), nmax) * 8];
            s0 = fmaf(m0, CVLO(A0.x), s0);
            s1 = fmaf(m0, CVHI(A0.x), s1);
            s2 = fmaf(m0, CVLO(A0.y), s2);
            s3 = fmaf(m0, CVHI(A0.y), s3);
            s4 = fmaf(m0, CVLO(A0.z), s4);
            s5 = fmaf(m0, CVHI(A0.z), s5);
            s6 = fmaf(m0, CVLO(A0.w), s6);
            s7 = fmaf(m0, CVHI(A0.w), s7);
        }
    }

    uint4 hreg; hreg.x = hreg.y = hreg.z = hreg.w = 0u;
    if (valid) {
        uint4 xv = xbf[(size_t)node * 8];            // bf16 self term
        float rinv = 1.0f / (float)(cnt + 1);
        float h0 = (s0 + CVLO(xv.x)) * rinv;
        float h1 = (s1 + CVHI(xv.x)) * rinv;
        float h2 = (s2 + CVLO(xv.y)) * rinv;
        float h3 = (s3 + CVHI(xv.y)) * rinv;
        float h4 = (s4 + CVLO(xv.z)) * rinv;
        float h5 = (s5 + CVHI(xv.z)) * rinv;
        float h6 = (s6 + CVLO(xv.w)) * rinv;
        float h7 = (s7 + CVHI(xv.w)) * rinv;
        hreg.x = (uint)f2bf(h0) | ((uint)f2bf(h1) << 16);
        hreg.y = (uint)f2bf(h2) | ((uint)f2bf(h3) << 16);
        hreg.z = (uint)f2bf(h4) | ((uint)f2bf(h5) << 16);
        hreg.w = (uint)f2bf(h6) | ((uint)f2bf(h7) << 16);
    }
#undef CVLO
#undef CVHI

    // All waves done with srt -> reuse it as the shared 64x64 bf16 h tile.
    __syncthreads();

    char* hstage = (char*)srt;               // 64 rows x 128B, swizzled
    *(uint4*)(hstage + nl * 128 + ((f8 * 16) ^ ((nl & 7) << 4))) = hreg;
    __syncthreads();

    // MFMA epilogue: waves 0..3 each handle one 16-node tile.
    if (wave < 4) {
        char* hwb = hstage + wave * 2048;
        const int m  = lane & 15;
        const int kg = lane >> 4;
        bf16x8 a0 = *(const bf16x8*)(hwb + m * 128 + (((kg * 16)     ) ^ ((m & 7) << 4)));
        bf16x8 a1 = *(const bf16x8*)(hwb + m * 128 + (((64 + kg * 16)) ^ ((m & 7) << 4)));

        const int node0 = (bucket << BSH) + wave * 16;
#pragma unroll
        for (int c = 0; c < 4; ++c) {
            const int o = c * 16 + m;
            bf16x8 b0 = *(const bf16x8*)((char*)Wl + o * 128 + (((kg * 16)     ) ^ ((o & 7) << 4)));
            bf16x8 b1 = *(const bf16x8*)((char*)Wl + o * 128 + (((64 + kg * 16)) ^ ((o & 7) << 4)));
            f32x4 acc = {0.f, 0.f, 0.f, 0.f};
            acc = __builtin_amdgcn_mfma_f32_16x16x32_bf16(a0, b0, acc, 0, 0, 0);
            acc = __builtin_amdgcn_mfma_f32_16x16x32_bf16(a1, b1, acc, 0, 0, 0);
            const float bias = bvec[o];
#pragma unroll
            for (int r = 0; r < 4; ++r) {
                int row = node0 + kg * 4 + r;
                if (row < n_nodes)
                    out[(size_t)row * 64 + o] = acc[r] + bias;
            }
        }
    }
}

extern "C" void kernel_launch(void* const* d_in, const int* in_sizes, int n_in,
                              void* d_out, int out_size, void* d_ws, size_t ws_size,
                              hipStream_t stream)
{
    const float* x   = (const float*)d_in[0];
    const int*   src = (const int*)d_in[1];
    const int*   dst = (const int*)d_in[2];
    const float* W   = (const float*)d_in[3];
    const float* b   = (const float*)d_in[4];
    float* out = (float*)d_out;

    const int n_nodes = in_sizes[0] / D;
    const int n_edges = in_sizes[1];
    const int nb  = (n_nodes + BSZ - 1) >> BSH;      // 64-node buckets (1563)
    const int nbS = (n_edges + STILE - 1) / STILE;   // scatter blocks (98)

    // Workspace: [xb (N+1)*64 bf16][gcnt NBMAX][packedB nb*CAPB]
    ushort_t* xb = (ushort_t*)d_ws;
    int* gcnt    = (int*)(xb + (size_t)(n_nodes + 1) * D);
    int* packedB = gcnt + NBMAX;

    hipMemsetAsync(gcnt, 0, NBMAX * sizeof(int), stream);

    const int n8 = n_nodes * D / 8;
    const int gridS = 391;                            // conv spread; >= nbS
    k_scatconv<<<gridS, 512, 0, stream>>>((const float4*)x, (uint4*)xb,
                                          src, dst, gcnt, packedB,
                                          n8, nb, nbS, n_edges);
    k_aggcsr  <<<nb,  512, 0, stream>>>(packedB, gcnt, (const uint4*)xb,
                                        W, b, out, n_nodes);
}

// Round 19
// 69.097 us; speedup vs baseline: 1.2068x; 1.0788x over previous
//
#include <hip/hip_runtime.h>

#define D 64
#define BSH 6            // bucket shift: 64 nodes per bucket
#define BSZ 64           // nodes per bucket
#define NBMAX 2048       // max buckets (nodes <= 131072)
#define STILE 8192       // edges per scatter block (196 blocks, runs ~5.2 edges)
#define CAPB 2048        // fixed bucket region stride (mean 1024, +32 sigma)
#define CAP  1536        // LDS edge-staging capacity in aggcsr (16 sigma)
#define SRTC 2056        // sorted+padded capacity (>= 8KB for h-staging reuse)

typedef unsigned int   uint;
typedef unsigned short ushort_t;
typedef __attribute__((ext_vector_type(8))) short bf16x8;
typedef __attribute__((ext_vector_type(4))) float f32x4;

__device__ __forceinline__ ushort_t f2bf(float f) {
    uint u = __float_as_uint(f);
    u += 0x7FFFu + ((u >> 16) & 1u);           // round-to-nearest-even
    return (ushort_t)(u >> 16);
}

// ---------------------------------------------------------------------------
// 1. Fused conv + one-pass scatter. ALL blocks (391) convert an x slice;
//    blocks < nbS (196) additionally scatter their 8K-edge tile into
//    fixed-stride bucket regions (LDS hist -> one global atomicAdd per
//    touched bucket -> scatter). STILE 8192 balances reservation run length
//    (~5.2 edges) against scatter-phase parallelism (196 blocks).
// ---------------------------------------------------------------------------
__global__ __launch_bounds__(512) void k_scatconv(
    const float4* __restrict__ x4, uint4* __restrict__ xb4,
    const int* __restrict__ src, const int* __restrict__ dst,
    int* __restrict__ gcnt, int* __restrict__ packedB,
    int n8, int nb, int nbS, int n_edges)
{
    __shared__ int hist[NBMAX];
    const int tid = threadIdx.x;
    const int blk = blockIdx.x;

    // Zero pad row (xb row n_nodes) once.
    if (blk == 0 && tid < 8) {
        uint4 z; z.x = z.y = z.z = z.w = 0u;
        xb4[n8 + tid] = z;
    }

    // bf16 conversion slice over ALL blocks (coalesced, full BW).
    {
        const int chunk = (n8 + gridDim.x - 1) / gridDim.x;
        const int lo = blk * chunk;
        const int hi = min(n8, lo + chunk);
        for (int t = lo + tid; t < hi; t += 512) {
            float4 a = x4[t * 2];
            float4 c = x4[t * 2 + 1];
            uint4 o;
            o.x = (uint)f2bf(a.x) | ((uint)f2bf(a.y) << 16);
            o.y = (uint)f2bf(a.z) | ((uint)f2bf(a.w) << 16);
            o.z = (uint)f2bf(c.x) | ((uint)f2bf(c.y) << 16);
            o.w = (uint)f2bf(c.z) | ((uint)f2bf(c.w) << 16);
            xb4[t] = o;
        }
    }

    if (blk >= nbS) return;

    for (int i = tid; i < nb; i += 512) hist[i] = 0;
    __syncthreads();

    const int e0 = blk * STILE;
    const int n4 = n_edges >> 2;
    const int4* src4 = (const int4*)src;
    const int4* dst4 = (const int4*)dst;

    // Pass 1: tile-local bucket histogram.
#pragma unroll
    for (int k = 0; k < STILE / 2048; ++k) {
        int i4 = (e0 >> 2) + k * 512 + tid;
        if (i4 < n4) {
            int4 d = dst4[i4];
            atomicAdd(&hist[d.x >> BSH], 1);
            atomicAdd(&hist[d.y >> BSH], 1);
            atomicAdd(&hist[d.z >> BSH], 1);
            atomicAdd(&hist[d.w >> BSH], 1);
        }
    }
    if (blk == nbS - 1) {
        for (int e = (n4 << 2) + tid; e < n_edges; e += 512)
            atomicAdd(&hist[dst[e] >> BSH], 1);
    }
    __syncthreads();

    // Reserve: hist[i] becomes this block's global cursor for bucket i.
    for (int i = tid; i < nb; i += 512) {
        int c = hist[i];
        if (c) hist[i] = atomicAdd(&gcnt[i], c);
    }
    __syncthreads();

    // Pass 2: scatter (tile is L2-hot from pass 1).
#pragma unroll
    for (int k = 0; k < STILE / 2048; ++k) {
        int i4 = (e0 >> 2) + k * 512 + tid;
        if (i4 < n4) {
            int4 sv = src4[i4];
            int4 dv = dst4[i4];
            int b, p;
            b = dv.x >> BSH; p = atomicAdd(&hist[b], 1);
            if (p < CAPB) packedB[(size_t)b * CAPB + p] = sv.x | ((dv.x & (BSZ-1)) << 24);
            b = dv.y >> BSH; p = atomicAdd(&hist[b], 1);
            if (p < CAPB) packedB[(size_t)b * CAPB + p] = sv.y | ((dv.y & (BSZ-1)) << 24);
            b = dv.z >> BSH; p = atomicAdd(&hist[b], 1);
            if (p < CAPB) packedB[(size_t)b * CAPB + p] = sv.z | ((dv.z & (BSZ-1)) << 24);
            b = dv.w >> BSH; p = atomicAdd(&hist[b], 1);
            if (p < CAPB) packedB[(size_t)b * CAPB + p] = sv.w | ((dv.w & (BSZ-1)) << 24);
        }
    }
    if (blk == nbS - 1) {
        for (int e = (n4 << 2) + tid; e < n_edges; e += 512) {
            int b = dst[e] >> BSH;
            int p = atomicAdd(&hist[b], 1);
            if (p < CAPB) packedB[(size_t)b * CAPB + p] = src[e] | ((dst[e] & (BSZ-1)) << 24);
        }
    }
}

// ---------------------------------------------------------------------------
// B. Fused per-bucket CSR + aggregate + MFMA GEMM + bias (r14/r17-proven,
//    unchanged). One block per 64-node bucket (512 thr, 8 waves, ~23KB LDS).
// ---------------------------------------------------------------------------
__global__ __launch_bounds__(512, 8) void k_aggcsr(
    const int* __restrict__ packedB, const int* __restrict__ gcnt,
    const uint4* __restrict__ xb4, const float* __restrict__ W,
    const float* __restrict__ bvec, float* __restrict__ out, int n_nodes)
{
    __shared__ int raw[CAP];
    __shared__ int srt[SRTC];             // sorted+padded; reused for h-staging
    __shared__ ushort_t Wl[64 * 64];      // bf16 W, XOR-swizzled rows
    __shared__ int ldeg[BSZ];
    __shared__ int lofs[BSZ];
    __shared__ int cur[BSZ];

    const int tid = threadIdx.x;
    const int bucket = blockIdx.x;
    const int ebase = bucket * CAPB;
    const int ecnt  = min(gcnt[bucket], CAPB);
    const bool fits = (ecnt <= CAP);
    const uint nmax = (uint)(n_nodes - 1);
    const int zrow = n_nodes;             // zeroed xb row for padding

    // Phase 0: stage W (fp32 -> bf16) into LDS with byte ^= (row&7)<<4 swizzle.
    {
        const int o = tid >> 3;            // row 0..63
        const int j = (tid & 7) * 8;       // col 0..56
        const float* wp = W + o * 64 + j;
        float4 wa = *(const float4*)wp;
        float4 wb = *(const float4*)(wp + 4);
        uint4 w4;
        w4.x = (uint)f2bf(wa.x) | ((uint)f2bf(wa.y) << 16);
        w4.y = (uint)f2bf(wa.z) | ((uint)f2bf(wa.w) << 16);
        w4.z = (uint)f2bf(wb.x) | ((uint)f2bf(wb.y) << 16);
        w4.w = (uint)f2bf(wb.z) | ((uint)f2bf(wb.w) << 16);
        *(uint4*)((char*)Wl + o * 128 + ((j * 2) ^ ((o & 7) << 4))) = w4;
    }
    if (tid < BSZ) ldeg[tid] = 0;
    __syncthreads();

    // Phase 1: stage edges + degree histogram.
    if (fits) {
        for (int i = tid; i < ecnt; i += 512) {
            int pk = packedB[ebase + i];
            raw[i] = pk;
            atomicAdd(&ldeg[((uint)pk) >> 24], 1);
        }
    } else {
        for (int i = tid; i < ecnt; i += 512)
            atomicAdd(&ldeg[((uint)packedB[ebase + i]) >> 24], 1);
    }
    __syncthreads();

    // Phase 2: exclusive scan of counts padded to x4 (first 64 threads).
    {
        int v = 0;
        if (tid < BSZ) { v = (ldeg[tid] + 3) & ~3; lofs[tid] = v; }
        __syncthreads();
        for (int off = 1; off < BSZ; off <<= 1) {
            int t = (tid < BSZ && tid >= off) ? lofs[tid - off] : 0;
            __syncthreads();
            if (tid < BSZ) lofs[tid] += t;
            __syncthreads();
        }
        if (tid < BSZ) { int e = lofs[tid] - v; lofs[tid] = e; cur[tid] = e; }
    }
    __syncthreads();

    // Phase 3: sort esrc into padded LDS segments + fill pads with zrow.
    if (fits) {
        for (int i = tid; i < ecnt; i += 512) {
            int pk = raw[i];
            int pos = atomicAdd(&cur[((uint)pk) >> 24], 1);
            srt[pos] = pk & 0x00FFFFFF;
        }
        if (tid < BSZ) {
            int base = lofs[tid] + ldeg[tid];
            int end  = lofs[tid] + ((ldeg[tid] + 3) & ~3);
            for (int i = base; i < end; ++i) srt[i] = zrow;
        }
    }
    __syncthreads();

    // Phase 4: gather. Wave w owns nodes w*8..w*8+7; group g (8 lanes) walks
    // node w*8+g serially; each lane holds 8 feats (uint4).
    const int wave = tid >> 6;
    const int lane = tid & 63;
    const int g    = lane >> 3;        // node group 0..7
    const int f8   = lane & 7;         // uint4 index within row (8 feats)

#define CVLO(u) __uint_as_float((u) << 16)
#define CVHI(u) __uint_as_float((u) & 0xFFFF0000u)

    const uint4* __restrict__ xbf = xb4 + f8;

    const int nl = wave * 8 + g;
    const int node = (bucket << BSH) + nl;
    const bool valid = (node < n_nodes);
    const int cnt = valid ? ldeg[nl] : 0;
    const int eb  = valid ? lofs[nl] : 0;
    const int pc  = (cnt + 3) & ~3;

    float s0 = 0.f, s1 = 0.f, s2 = 0.f, s3 = 0.f;
    float s4 = 0.f, s5 = 0.f, s6 = 0.f, s7 = 0.f;

    if (fits) {
        for (int i = 0; i < pc; i += 4) {
            uint vv[4];
#pragma unroll
            for (int k = 0; k < 4; ++k) vv[k] = (uint)srt[eb + i + k];
            uint4 A[4];
#pragma unroll
            for (int k = 0; k < 4; ++k)
                A[k] = xbf[(size_t)vv[k] * 8];
#pragma unroll
            for (int k = 0; k < 4; ++k) {
                s0 += CVLO(A[k].x);
                s1 += CVHI(A[k].x);
                s2 += CVLO(A[k].y);
                s3 += CVHI(A[k].y);
                s4 += CVLO(A[k].z);
                s5 += CVHI(A[k].z);
                s6 += CVLO(A[k].w);
                s7 += CVHI(A[k].w);
            }
        }
    } else {
        // Fallback (never hit for this input): masked scan of bucket.
        const int nlm = valid ? nl : -1;
        for (int i = 0; i < ecnt; ++i) {
            int pk = packedB[ebase + i];
            float m0 = ((int)(((uint)pk) >> 24) == nlm) ? 1.0f : 0.0f;
            uint4 A0 = xbf[(size_t)min((uint)(pk & 0x00FFFFFF), nmax) * 8];
            s0 = fmaf(m0, CVLO(A0.x), s0);
            s1 = fmaf(m0, CVHI(A0.x), s1);
            s2 = fmaf(m0, CVLO(A0.y), s2);
            s3 = fmaf(m0, CVHI(A0.y), s3);
            s4 = fmaf(m0, CVLO(A0.z), s4);
            s5 = fmaf(m0, CVHI(A0.z), s5);
            s6 = fmaf(m0, CVLO(A0.w), s6);
            s7 = fmaf(m0, CVHI(A0.w), s7);
        }
    }

    uint4 hreg; hreg.x = hreg.y = hreg.z = hreg.w = 0u;
    if (valid) {
        uint4 xv = xbf[(size_t)node * 8];            // bf16 self term
        float rinv = 1.0f / (float)(cnt + 1);
        float h0 = (s0 + CVLO(xv.x)) * rinv;
        float h1 = (s1 + CVHI(xv.x)) * rinv;
        float h2 = (s2 + CVLO(xv.y)) * rinv;
        float h3 = (s3 + CVHI(xv.y)) * rinv;
        float h4 = (s4 + CVLO(xv.z)) * rinv;
        float h5 = (s5 + CVHI(xv.z)) * rinv;
        float h6 = (s6 + CVLO(xv.w)) * rinv;
        float h7 = (s7 + CVHI(xv.w)) * rinv;
        hreg.x = (uint)f2bf(h0) | ((uint)f2bf(h1) << 16);
        hreg.y = (uint)f2bf(h2) | ((uint)f2bf(h3) << 16);
        hreg.z = (uint)f2bf(h4) | ((uint)f2bf(h5) << 16);
        hreg.w = (uint)f2bf(h6) | ((uint)f2bf(h7) << 16);
    }
#undef CVLO
#undef CVHI

    // All waves done with srt -> reuse it as the shared 64x64 bf16 h tile.
    __syncthreads();

    char* hstage = (char*)srt;               // 64 rows x 128B, swizzled
    *(uint4*)(hstage + nl * 128 + ((f8 * 16) ^ ((nl & 7) << 4))) = hreg;
    __syncthreads();

    // MFMA epilogue: waves 0..3 each handle one 16-node tile.
    if (wave < 4) {
        char* hwb = hstage + wave * 2048;
        const int m  = lane & 15;
        const int kg = lane >> 4;
        bf16x8 a0 = *(const bf16x8*)(hwb + m * 128 + (((kg * 16)     ) ^ ((m & 7) << 4)));
        bf16x8 a1 = *(const bf16x8*)(hwb + m * 128 + (((64 + kg * 16)) ^ ((m & 7) << 4)));

        const int node0 = (bucket << BSH) + wave * 16;
#pragma unroll
        for (int c = 0; c < 4; ++c) {
            const int o = c * 16 + m;
            bf16x8 b0 = *(const bf16x8*)((char*)Wl + o * 128 + (((kg * 16)     ) ^ ((o & 7) << 4)));
            bf16x8 b1 = *(const bf16x8*)((char*)Wl + o * 128 + (((64 + kg * 16)) ^ ((o & 7) << 4)));
            f32x4 acc = {0.f, 0.f, 0.f, 0.f};
            acc = __builtin_amdgcn_mfma_f32_16x16x32_bf16(a0, b0, acc, 0, 0, 0);
            acc = __builtin_amdgcn_mfma_f32_16x16x32_bf16(a1, b1, acc, 0, 0, 0);
            const float bias = bvec[o];
#pragma unroll
            for (int r = 0; r < 4; ++r) {
                int row = node0 + kg * 4 + r;
                if (row < n_nodes)
                    out[(size_t)row * 64 + o] = acc[r] + bias;
            }
        }
    }
}

extern "C" void kernel_launch(void* const* d_in, const int* in_sizes, int n_in,
                              void* d_out, int out_size, void* d_ws, size_t ws_size,
                              hipStream_t stream)
{
    const float* x   = (const float*)d_in[0];
    const int*   src = (const int*)d_in[1];
    const int*   dst = (const int*)d_in[2];
    const float* W   = (const float*)d_in[3];
    const float* b   = (const float*)d_in[4];
    float* out = (float*)d_out;

    const int n_nodes = in_sizes[0] / D;
    const int n_edges = in_sizes[1];
    const int nb  = (n_nodes + BSZ - 1) >> BSH;      // 64-node buckets (1563)
    const int nbS = (n_edges + STILE - 1) / STILE;   // scatter blocks (196)

    // Workspace: [xb (N+1)*64 bf16][gcnt NBMAX][packedB nb*CAPB]
    ushort_t* xb = (ushort_t*)d_ws;
    int* gcnt    = (int*)(xb + (size_t)(n_nodes + 1) * D);
    int* packedB = gcnt + NBMAX;

    hipMemsetAsync(gcnt, 0, NBMAX * sizeof(int), stream);

    const int n8 = n_nodes * D / 8;
    const int gridS = 391;                            // conv spread; >= nbS
    k_scatconv<<<gridS, 512, 0, stream>>>((const float4*)x, (uint4*)xb,
                                          src, dst, gcnt, packedB,
                                          n8, nb, nbS, n_edges);
    k_aggcsr  <<<nb,  512, 0, stream>>>(packedB, gcnt, (const uint4*)xb,
                                        W, b, out, n_nodes);
}